// Round 1
// baseline (967.009 us; speedup 1.0000x reference)
//
#include <hip/hip_runtime.h>
#include <stdint.h>

#define BATCH 65536
#define KCAT 832   // 320 (state+action) + 512 (h)

typedef __attribute__((ext_vector_type(8))) short bf16x8;
typedef __attribute__((ext_vector_type(4))) float f32x4;

typedef __attribute__((address_space(3))) void lds_void_t;
typedef __attribute__((address_space(1))) void glob_void_t;

__device__ __forceinline__ void async_copy16(const void* g, void* l) {
  // 16B per lane, global -> LDS direct (wave-uniform LDS base + lane*16)
  __builtin_amdgcn_global_load_lds((glob_void_t*)(uintptr_t)g,
                                   (lds_void_t*)(uint32_t)(uintptr_t)l, 16, 0, 0);
}

__device__ __forceinline__ float b2f(unsigned short u) {
  union { uint32_t i; float f; } c; c.i = ((uint32_t)u) << 16; return c.f;
}
__device__ __forceinline__ unsigned short f2b(float f) {
  uint32_t x = __float_as_uint(f);
  uint32_t r = (x + 0x7fffu + ((x >> 16) & 1u)) >> 16;
  return (unsigned short)r;
}

// ---------------- prep kernels ----------------

__global__ void pack_A(const float* __restrict__ state, const float* __restrict__ action,
                       const float* __restrict__ hidden, unsigned short* __restrict__ Acat) {
  long t = (long)blockIdx.x * 256 + threadIdx.x;   // 65536*104 threads
  int seg = (int)(t % 104); long row = t / 104;
  int col = seg * 8;
  const float* src;
  if (col < 256)       src = state  + row * 256 + col;
  else if (col < 320)  src = action + row * 64  + (col - 256);
  else                 src = hidden + row * 512 + (col - 320);
  bf16x8 o;
  #pragma unroll
  for (int j = 0; j < 8; j++) o[j] = (short)f2b(src[j]);
  *(bf16x8*)(Acat + row * (size_t)KCAT + col) = o;
}

__global__ void pack_W(const float* __restrict__ w_ih, const float* __restrict__ w_hh,
                       unsigned short* __restrict__ Wrz, unsigned short* __restrict__ Wn) {
  long t = (long)blockIdx.x * 256 + threadIdx.x;   // 1536*104 threads
  int seg = (int)(t % 104); int j = (int)(t / 104); // row 0..1535
  int col = seg * 8;
  const float* src = (col < 320) ? (w_ih + (long)j * 320 + col)
                                 : (w_hh + (long)j * 512 + (col - 320));
  unsigned short* dst = (j < 1024) ? (Wrz + (long)j * KCAT + col)
                                   : (Wn + (long)(j - 1024) * KCAT + col);
  bf16x8 o;
  #pragma unroll
  for (int jj = 0; jj < 8; jj++) o[jj] = (short)f2b(src[jj]);
  *(bf16x8*)dst = o;
}

__global__ void pack_w12(const float* __restrict__ w1, const float* __restrict__ w2,
                         const float* __restrict__ b_ih, const float* __restrict__ b_hh,
                         unsigned short* __restrict__ w1b, unsigned short* __restrict__ w2b,
                         float* __restrict__ brz) {
  long t = (long)blockIdx.x * 256 + threadIdx.x;
  if (t < 65536) {
    const float* s = w1 + t * 8; unsigned short* d = w1b + t * 8;
    bf16x8 o;
    #pragma unroll
    for (int j = 0; j < 8; j++) o[j] = (short)f2b(s[j]);
    *(bf16x8*)d = o;
  } else if (t < 65536 + 131072) {
    long t2 = t - 65536;
    const float* s = w2 + t2 * 8; unsigned short* d = w2b + t2 * 8;
    bf16x8 o;
    #pragma unroll
    for (int j = 0; j < 8; j++) o[j] = (short)f2b(s[j]);
    *(bf16x8*)d = o;
  } else if (t < 65536 + 131072 + 128) {
    int i = (int)(t - (65536 + 131072)) * 8;
    #pragma unroll
    for (int j = 0; j < 8; j++) brz[i + j] = b_ih[i + j] + b_hh[i + j];
  }
}

// ---------------- generic TN GEMM: C = act(A @ W^T + bias), bf16 out ----------------
// A: [M x lda] bf16 row-major, W: [N x lda] bf16 row-major. 128x128 tile, BK=64.
// EPI 0 = sigmoid, 1 = relu.

template<int KT, int EPI>
__global__ __launch_bounds__(256, 2) void gemm_bt(
    const unsigned short* __restrict__ A, const unsigned short* __restrict__ W,
    const float* __restrict__ bias, unsigned short* __restrict__ out,
    int lda, int N)
{
  __shared__ unsigned short Asm[128 * 64];
  __shared__ unsigned short Bsm[128 * 64];
  const int tid = threadIdx.x;
  const int wave = tid >> 6, lane = tid & 63;
  const int wm = wave >> 1, wn = wave & 1;
  const long bm = blockIdx.y, bn = blockIdx.x;
  const int srow = lane >> 3;        // 0..7
  const int scol = (lane & 7) * 8;   // staging k offset (elements)

  f32x4 acc[4][4];
  #pragma unroll
  for (int i = 0; i < 4; i++)
    #pragma unroll
    for (int j = 0; j < 4; j++) acc[i][j] = (f32x4){0.f, 0.f, 0.f, 0.f};

  const unsigned short* Ag = A + (bm * 128 + wave * 8 + srow) * (size_t)lda + scol;
  const unsigned short* Wg = W + (bn * 128 + wave * 8 + srow) * (size_t)lda + scol;

  for (int kt = 0; kt < KT; ++kt) {
    __syncthreads();
    #pragma unroll
    for (int t = 0; t < 4; ++t)
      async_copy16(Ag + (size_t)(t * 32) * lda + kt * 64, &Asm[(t * 32 + wave * 8) * 64]);
    #pragma unroll
    for (int t = 0; t < 4; ++t)
      async_copy16(Wg + (size_t)(t * 32) * lda + kt * 64, &Bsm[(t * 32 + wave * 8) * 64]);
    __syncthreads();

    #pragma unroll
    for (int ks = 0; ks < 2; ++ks) {
      const int kcol = ks * 32 + (lane >> 4) * 8;
      bf16x8 af[4], bfv[4];
      #pragma unroll
      for (int mt = 0; mt < 4; mt++)
        af[mt] = *(const bf16x8*)&Asm[(wm * 64 + mt * 16 + (lane & 15)) * 64 + kcol];
      #pragma unroll
      for (int nt = 0; nt < 4; nt++)
        bfv[nt] = *(const bf16x8*)&Bsm[(wn * 64 + nt * 16 + (lane & 15)) * 64 + kcol];
      #pragma unroll
      for (int mt = 0; mt < 4; mt++)
        #pragma unroll
        for (int nt = 0; nt < 4; nt++)
          acc[mt][nt] = __builtin_amdgcn_mfma_f32_16x16x32_bf16(af[mt], bfv[nt], acc[mt][nt], 0, 0, 0);
    }
  }

  // epilogue: C/D layout col=lane&15, row=quad*4+reg
  #pragma unroll
  for (int mt = 0; mt < 4; mt++) {
    #pragma unroll
    for (int nt = 0; nt < 4; nt++) {
      const int col = (int)bn * 128 + wn * 64 + nt * 16 + (lane & 15);
      const float bv = bias[col];
      #pragma unroll
      for (int i = 0; i < 4; i++) {
        const long row = bm * 128 + wm * 64 + mt * 16 + (lane >> 4) * 4 + i;
        float v = acc[mt][nt][i] + bv;
        if (EPI == 0) v = 1.f / (1.f + __expf(-v));
        else          v = fmaxf(v, 0.f);
        out[row * (size_t)N + col] = f2b(v);
      }
    }
  }
}

// ---------------- GRU n-gate GEMM + fused GRU elementwise ----------------
// Computes i_n (k-tiles 0..4 of A_cat/Wn) and h_n (k-tiles 5..12) into separate
// accumulators; epilogue: n = tanh(i_n + b_in + r*(h_n + b_hn)), h_new = (1-z)n + z h.
// Tile 128x64, BK=64.

__global__ __launch_bounds__(256, 2) void gru_gemm(
    const unsigned short* __restrict__ A,    // A_cat [BATCH x 832]
    const unsigned short* __restrict__ Wn,   // [512 x 832]
    const float* __restrict__ b_ih, const float* __restrict__ b_hh,
    const unsigned short* __restrict__ rz,   // [BATCH x 1024] bf16 (r | z), post-sigmoid
    const float* __restrict__ hidden,        // [BATCH x 512] f32
    float* __restrict__ hnew_f,              // d_out + BATCH
    unsigned short* __restrict__ hnew_b)     // bf16 copy for next GEMM
{
  __shared__ unsigned short Asm[128 * 64];
  __shared__ unsigned short Bsm[64 * 64];
  const int tid = threadIdx.x;
  const int wave = tid >> 6, lane = tid & 63;
  const int wm = wave >> 1, wn = wave & 1;
  const long bm = blockIdx.y, bn = blockIdx.x;
  const int srow = lane >> 3;
  const int scol = (lane & 7) * 8;

  f32x4 aI[4][2], aH[4][2];
  #pragma unroll
  for (int i = 0; i < 4; i++)
    #pragma unroll
    for (int j = 0; j < 2; j++) {
      aI[i][j] = (f32x4){0.f, 0.f, 0.f, 0.f};
      aH[i][j] = (f32x4){0.f, 0.f, 0.f, 0.f};
    }

  const unsigned short* Ag = A  + (bm * 128 + wave * 8 + srow) * (size_t)KCAT + scol;
  const unsigned short* Wg = Wn + (bn * 64  + wave * 8 + srow) * (size_t)KCAT + scol;

  for (int kt = 0; kt < 13; ++kt) {
    __syncthreads();
    #pragma unroll
    for (int t = 0; t < 4; ++t)
      async_copy16(Ag + (size_t)(t * 32) * KCAT + kt * 64, &Asm[(t * 32 + wave * 8) * 64]);
    #pragma unroll
    for (int t = 0; t < 2; ++t)
      async_copy16(Wg + (size_t)(t * 32) * KCAT + kt * 64, &Bsm[(t * 32 + wave * 8) * 64]);
    __syncthreads();

    #pragma unroll
    for (int ks = 0; ks < 2; ++ks) {
      const int kcol = ks * 32 + (lane >> 4) * 8;
      bf16x8 af[4], bfv[2];
      #pragma unroll
      for (int mt = 0; mt < 4; mt++)
        af[mt] = *(const bf16x8*)&Asm[(wm * 64 + mt * 16 + (lane & 15)) * 64 + kcol];
      #pragma unroll
      for (int nt = 0; nt < 2; nt++)
        bfv[nt] = *(const bf16x8*)&Bsm[(wn * 32 + nt * 16 + (lane & 15)) * 64 + kcol];
      if (kt < 5) {
        #pragma unroll
        for (int mt = 0; mt < 4; mt++)
          #pragma unroll
          for (int nt = 0; nt < 2; nt++)
            aI[mt][nt] = __builtin_amdgcn_mfma_f32_16x16x32_bf16(af[mt], bfv[nt], aI[mt][nt], 0, 0, 0);
      } else {
        #pragma unroll
        for (int mt = 0; mt < 4; mt++)
          #pragma unroll
          for (int nt = 0; nt < 2; nt++)
            aH[mt][nt] = __builtin_amdgcn_mfma_f32_16x16x32_bf16(af[mt], bfv[nt], aH[mt][nt], 0, 0, 0);
      }
    }
  }

  const long rowbase = bm * 128 + wm * 64;
  const int colbase = (int)bn * 64 + wn * 32;
  #pragma unroll
  for (int mt = 0; mt < 4; mt++) {
    #pragma unroll
    for (int nt = 0; nt < 2; nt++) {
      const int col = colbase + nt * 16 + (lane & 15);   // 0..511
      const float bin = b_ih[1024 + col];
      const float bhn = b_hh[1024 + col];
      #pragma unroll
      for (int i = 0; i < 4; i++) {
        const long row = rowbase + mt * 16 + (lane >> 4) * 4 + i;
        const float iN = aI[mt][nt][i] + bin;
        const float hN = aH[mt][nt][i] + bhn;
        const float r = b2f(rz[row * (size_t)1024 + col]);
        const float z = b2f(rz[row * (size_t)1024 + 512 + col]);
        const float x = iN + r * hN;
        const float n = 1.f - 2.f / (__expf(2.f * x) + 1.f);   // tanh(x)
        const float h = hidden[row * (size_t)512 + col];
        const float hv = (1.f - z) * n + z * h;
        hnew_f[row * (size_t)512 + col] = hv;
        hnew_b[row * (size_t)512 + col] = f2b(hv);
      }
    }
  }
}

// ---------------- q = x2 @ w3^T + b3 (one wave per row) ----------------

__global__ void qdot(const unsigned short* __restrict__ x2, const float* __restrict__ w3,
                     const float* __restrict__ b3, float* __restrict__ q) {
  const int lane = threadIdx.x & 63;
  const long row = (long)blockIdx.x * 4 + (threadIdx.x >> 6);
  const unsigned short* xr = x2 + row * (size_t)1024 + lane * 8;
  bf16x8 v0 = *(const bf16x8*)xr;
  bf16x8 v1 = *(const bf16x8*)(xr + 512);
  float s = 0.f;
  #pragma unroll
  for (int j = 0; j < 8; j++) {
    s += b2f((unsigned short)v0[j]) * w3[lane * 8 + j];
    s += b2f((unsigned short)v1[j]) * w3[512 + lane * 8 + j];
  }
  #pragma unroll
  for (int off = 32; off > 0; off >>= 1) s += __shfl_down(s, off, 64);
  if (lane == 0) q[row] = s + b3[0];
}

// ---------------- launch ----------------

extern "C" void kernel_launch(void* const* d_in, const int* in_sizes, int n_in,
                              void* d_out, int out_size, void* d_ws, size_t ws_size,
                              hipStream_t stream) {
  const float* state  = (const float*)d_in[0];
  const float* action = (const float*)d_in[1];
  const float* hidden = (const float*)d_in[2];
  const float* w_ih   = (const float*)d_in[3];
  const float* w_hh   = (const float*)d_in[4];
  const float* b_ih   = (const float*)d_in[5];
  const float* b_hh   = (const float*)d_in[6];
  const float* w1     = (const float*)d_in[7];
  const float* b1     = (const float*)d_in[8];
  const float* w2     = (const float*)d_in[9];
  const float* b2     = (const float*)d_in[10];
  const float* w3     = (const float*)d_in[11];
  const float* b3     = (const float*)d_in[12];

  float* q_out = (float*)d_out;
  float* h_out = q_out + BATCH;

  char* ws = (char*)d_ws;
  unsigned short* Acat = (unsigned short*)(ws + 0);            // 65536x832 bf16 (104MB; region 128MB)
  unsigned short* rz   = (unsigned short*)(ws + 134217728);    // 65536x1024 bf16 (128MB)
  unsigned short* hnb  = (unsigned short*)(ws + 268435456);    // 65536x512 bf16 (64MB)
  unsigned short* Wrz  = (unsigned short*)(ws + 335544320);    // 1024x832 bf16
  unsigned short* Wn   = (unsigned short*)(ws + 337248256);    // 512x832 bf16
  unsigned short* w1b  = (unsigned short*)(ws + 338100224);    // 1024x512 bf16
  unsigned short* w2b  = (unsigned short*)(ws + 339148800);    // 1024x1024 bf16
  float*          brz  = (float*)(ws + 341245952);             // 1024 f32
  unsigned short* x1   = Acat;  // reuse: A_cat dead after gru_gemm
  unsigned short* x2   = rz;    // reuse: rz dead after gru_gemm

  pack_A<<<26624, 256, 0, stream>>>(state, action, hidden, Acat);
  pack_W<<<624, 256, 0, stream>>>(w_ih, w_hh, Wrz, Wn);
  pack_w12<<<769, 256, 0, stream>>>(w1, w2, b_ih, b_hh, w1b, w2b, brz);

  // rz = sigmoid(A_cat @ Wrz^T + brz)   [65536 x 1024], K=832
  gemm_bt<13, 0><<<dim3(8, 512), 256, 0, stream>>>(Acat, Wrz, brz, rz, KCAT, 1024);
  // h_new (fused GRU), K=832 split 320/512
  gru_gemm<<<dim3(8, 512), 256, 0, stream>>>(Acat, Wn, b_ih, b_hh, rz, hidden, h_out, hnb);
  // x1 = relu(h_new @ w1^T + b1)  K=512
  gemm_bt<8, 1><<<dim3(8, 512), 256, 0, stream>>>(hnb, w1b, b1, x1, 512, 1024);
  // x2 = relu(x1 @ w2^T + b2)     K=1024
  gemm_bt<16, 1><<<dim3(8, 512), 256, 0, stream>>>(x1, w2b, b2, x2, 1024, 1024);
  // q = x2 @ w3^T + b3
  qdot<<<16384, 256, 0, stream>>>(x2, w3, b3, q_out);
}

// Round 2
// 821.433 us; speedup vs baseline: 1.1772x; 1.1772x over previous
//
#include <hip/hip_runtime.h>
#include <stdint.h>

#define BATCH 65536
#define KCAT 832   // 320 (state+action) + 512 (h)

typedef __attribute__((ext_vector_type(8))) short bf16x8;
typedef __attribute__((ext_vector_type(4))) float f32x4;

typedef __attribute__((address_space(3))) void lds_void_t;
typedef __attribute__((address_space(1))) void glob_void_t;

__device__ __forceinline__ void async_copy16(const void* g, void* l) {
  __builtin_amdgcn_global_load_lds((glob_void_t*)(uintptr_t)g,
                                   (lds_void_t*)(uint32_t)(uintptr_t)l, 16, 0, 0);
}

__device__ __forceinline__ float b2f(unsigned short u) {
  union { uint32_t i; float f; } c; c.i = ((uint32_t)u) << 16; return c.f;
}
__device__ __forceinline__ unsigned short f2b(float f) {
  uint32_t x = __float_as_uint(f);
  uint32_t r = (x + 0x7fffu + ((x >> 16) & 1u)) >> 16;
  return (unsigned short)r;
}

// ---------------- prep kernels ----------------

__global__ void pack_A(const float* __restrict__ state, const float* __restrict__ action,
                       const float* __restrict__ hidden, unsigned short* __restrict__ Acat) {
  long t = (long)blockIdx.x * 256 + threadIdx.x;   // 65536*104 threads
  int seg = (int)(t % 104); long row = t / 104;
  int col = seg * 8;
  const float* src;
  if (col < 256)       src = state  + row * 256 + col;
  else if (col < 320)  src = action + row * 64  + (col - 256);
  else                 src = hidden + row * 512 + (col - 320);
  bf16x8 o;
  #pragma unroll
  for (int j = 0; j < 8; j++) o[j] = (short)f2b(src[j]);
  *(bf16x8*)(Acat + row * (size_t)KCAT + col) = o;
}

__global__ void pack_W(const float* __restrict__ w_ih, const float* __restrict__ w_hh,
                       unsigned short* __restrict__ Wrz, unsigned short* __restrict__ Wn) {
  long t = (long)blockIdx.x * 256 + threadIdx.x;   // 1536*104 threads
  int seg = (int)(t % 104); int j = (int)(t / 104); // row 0..1535
  int col = seg * 8;
  const float* src = (col < 320) ? (w_ih + (long)j * 320 + col)
                                 : (w_hh + (long)j * 512 + (col - 320));
  unsigned short* dst = (j < 1024) ? (Wrz + (long)j * KCAT + col)
                                   : (Wn + (long)(j - 1024) * KCAT + col);
  bf16x8 o;
  #pragma unroll
  for (int jj = 0; jj < 8; jj++) o[jj] = (short)f2b(src[jj]);
  *(bf16x8*)dst = o;
}

__global__ void pack_w12(const float* __restrict__ w1, const float* __restrict__ w2,
                         unsigned short* __restrict__ w1b, unsigned short* __restrict__ w2b) {
  long t = (long)blockIdx.x * 256 + threadIdx.x;   // 196608 threads
  const float* s; unsigned short* d;
  if (t < 65536) { s = w1 + t * 8; d = w1b + t * 8; }
  else           { long t2 = t - 65536; s = w2 + t2 * 8; d = w2b + t2 * 8; }
  bf16x8 o;
  #pragma unroll
  for (int j = 0; j < 8; j++) o[j] = (short)f2b(s[j]);
  *(bf16x8*)d = o;
}

// ---------------- fused GRU: r,z,n GEMMs + elementwise ----------------
// Per block: 128 rows x 64 gate-cols. Accumulates r,z (K=832) and i_n (K=320),
// h_n (K=512) in registers; epilogue applies the full GRU cell.
// Grid: 4096 1-D, XCD-swizzled so the 8 bn-tiles of one bm share an XCD's L2.

__global__ __launch_bounds__(256, 2) void gru_fused(
    const unsigned short* __restrict__ A,    // A_cat [BATCH x 832] bf16
    const unsigned short* __restrict__ Wrz,  // [1024 x 832] bf16 (r rows 0..511, z rows 512..1023)
    const unsigned short* __restrict__ Wn,   // [512 x 832] bf16
    const float* __restrict__ b_ih, const float* __restrict__ b_hh,
    float* __restrict__ hnew_f,              // d_out + BATCH, f32 [BATCH x 512]
    unsigned short* __restrict__ hnew_b)     // bf16 copy for next GEMM
{
  __shared__ unsigned short Asm[128 * 64];       // 16 KB
  __shared__ unsigned short Wsm[3 * 64 * 64];    // 24 KB (r | z | n)
  const int tid = threadIdx.x;
  const int wave = tid >> 6, lane = tid & 63;
  const int wm = wave >> 1, wn = wave & 1;

  const int bid = blockIdx.x;
  const int xcd = bid & 7;
  const int j = bid >> 3;          // 0..511 per-XCD work id
  const int bn = j & 7;            // 8 col tiles of 64
  const long bm = (long)xcd * 64 + (j >> 3);   // 512 row tiles of 128

  const int srow = lane >> 3;        // 0..7
  const int scol = (lane & 7) * 8;   // staging k offset (elements)

  f32x4 accR[4][2], accZ[4][2], accI[4][2], accH[4][2];
  #pragma unroll
  for (int i = 0; i < 4; i++)
    #pragma unroll
    for (int t = 0; t < 2; t++) {
      accR[i][t] = (f32x4){0.f,0.f,0.f,0.f}; accZ[i][t] = (f32x4){0.f,0.f,0.f,0.f};
      accI[i][t] = (f32x4){0.f,0.f,0.f,0.f}; accH[i][t] = (f32x4){0.f,0.f,0.f,0.f};
    }

  const unsigned short* Ag  = A   + (bm * 128 + wave * 8 + srow) * (size_t)KCAT + scol;
  const unsigned short* Wrg = Wrz + ((size_t)bn * 64 + wave * 8 + srow) * KCAT + scol;
  const unsigned short* Wzg = Wrz + ((size_t)512 + bn * 64 + wave * 8 + srow) * KCAT + scol;
  const unsigned short* Wng = Wn  + ((size_t)bn * 64 + wave * 8 + srow) * KCAT + scol;

  for (int kt = 0; kt < 13; ++kt) {
    __syncthreads();
    #pragma unroll
    for (int t = 0; t < 4; ++t)
      async_copy16(Ag + (size_t)(t * 32) * KCAT + kt * 64, &Asm[(t * 32 + wave * 8) * 64]);
    #pragma unroll
    for (int t = 0; t < 2; ++t) {
      async_copy16(Wrg + (size_t)(t * 32) * KCAT + kt * 64, &Wsm[0 * 4096 + (t * 32 + wave * 8) * 64]);
      async_copy16(Wzg + (size_t)(t * 32) * KCAT + kt * 64, &Wsm[1 * 4096 + (t * 32 + wave * 8) * 64]);
      async_copy16(Wng + (size_t)(t * 32) * KCAT + kt * 64, &Wsm[2 * 4096 + (t * 32 + wave * 8) * 64]);
    }
    __syncthreads();

    #pragma unroll
    for (int ks = 0; ks < 2; ++ks) {
      const int kcol = ks * 32 + (lane >> 4) * 8;
      bf16x8 af[4], bR[2], bZ[2], bN[2];
      #pragma unroll
      for (int mt = 0; mt < 4; mt++)
        af[mt] = *(const bf16x8*)&Asm[(wm * 64 + mt * 16 + (lane & 15)) * 64 + kcol];
      #pragma unroll
      for (int nt = 0; nt < 2; nt++) {
        const int wrow = (wn * 32 + nt * 16 + (lane & 15)) * 64 + kcol;
        bR[nt] = *(const bf16x8*)&Wsm[0 * 4096 + wrow];
        bZ[nt] = *(const bf16x8*)&Wsm[1 * 4096 + wrow];
        bN[nt] = *(const bf16x8*)&Wsm[2 * 4096 + wrow];
      }
      #pragma unroll
      for (int mt = 0; mt < 4; mt++)
        #pragma unroll
        for (int nt = 0; nt < 2; nt++) {
          accR[mt][nt] = __builtin_amdgcn_mfma_f32_16x16x32_bf16(af[mt], bR[nt], accR[mt][nt], 0, 0, 0);
          accZ[mt][nt] = __builtin_amdgcn_mfma_f32_16x16x32_bf16(af[mt], bZ[nt], accZ[mt][nt], 0, 0, 0);
        }
      if (kt < 5) {   // k in [0,320): state+action part -> i_n
        #pragma unroll
        for (int mt = 0; mt < 4; mt++)
          #pragma unroll
          for (int nt = 0; nt < 2; nt++)
            accI[mt][nt] = __builtin_amdgcn_mfma_f32_16x16x32_bf16(af[mt], bN[nt], accI[mt][nt], 0, 0, 0);
      } else {        // k in [320,832): h part -> h_n
        #pragma unroll
        for (int mt = 0; mt < 4; mt++)
          #pragma unroll
          for (int nt = 0; nt < 2; nt++)
            accH[mt][nt] = __builtin_amdgcn_mfma_f32_16x16x32_bf16(af[mt], bN[nt], accH[mt][nt], 0, 0, 0);
      }
    }
  }

  // epilogue: C/D layout col=lane&15, row=quad*4+reg
  const long rowbase = bm * 128 + wm * 64;
  const int colbase = bn * 64 + wn * 32;
  #pragma unroll
  for (int mt = 0; mt < 4; mt++) {
    #pragma unroll
    for (int nt = 0; nt < 2; nt++) {
      const int col = colbase + nt * 16 + (lane & 15);   // 0..511
      const float brv = b_ih[col] + b_hh[col];
      const float bzv = b_ih[512 + col] + b_hh[512 + col];
      const float bin = b_ih[1024 + col];
      const float bhn = b_hh[1024 + col];
      #pragma unroll
      for (int i = 0; i < 4; i++) {
        const long row = rowbase + mt * 16 + (lane >> 4) * 4 + i;
        const float r = 1.f / (1.f + __expf(-(accR[mt][nt][i] + brv)));
        const float z = 1.f / (1.f + __expf(-(accZ[mt][nt][i] + bzv)));
        const float x = (accI[mt][nt][i] + bin) + r * (accH[mt][nt][i] + bhn);
        const float n = 1.f - 2.f / (__expf(2.f * x) + 1.f);   // tanh(x)
        const float h = b2f(A[row * (size_t)KCAT + 320 + col]); // h in bf16 from A_cat
        const float hv = (1.f - z) * n + z * h;
        hnew_f[row * (size_t)512 + col] = hv;
        hnew_b[row * (size_t)512 + col] = f2b(hv);
      }
    }
  }
}

// ---------------- generic TN GEMM: C = relu(A @ W^T + bias), bf16 out ----------------
// 128x128 tile, BK=64, XCD-swizzled 1-D grid of 4096 (M=65536, N=1024).

template<int KT>
__global__ __launch_bounds__(256, 2) void gemm_bt(
    const unsigned short* __restrict__ A, const unsigned short* __restrict__ W,
    const float* __restrict__ bias, unsigned short* __restrict__ out,
    int lda)
{
  __shared__ unsigned short Asm[128 * 64];
  __shared__ unsigned short Bsm[128 * 64];
  const int tid = threadIdx.x;
  const int wave = tid >> 6, lane = tid & 63;
  const int wm = wave >> 1, wn = wave & 1;

  const int bid = blockIdx.x;
  const int xcd = bid & 7;
  const int j = bid >> 3;
  const int bn = j & 7;                        // 8 col tiles of 128 (N=1024)
  const long bm = (long)xcd * 64 + (j >> 3);   // 512 row tiles of 128

  const int srow = lane >> 3;
  const int scol = (lane & 7) * 8;

  f32x4 acc[4][4];
  #pragma unroll
  for (int i = 0; i < 4; i++)
    #pragma unroll
    for (int t = 0; t < 4; t++) acc[i][t] = (f32x4){0.f, 0.f, 0.f, 0.f};

  const unsigned short* Ag = A + (bm * 128 + wave * 8 + srow) * (size_t)lda + scol;
  const unsigned short* Wg = W + ((size_t)bn * 128 + wave * 8 + srow) * lda + scol;

  for (int kt = 0; kt < KT; ++kt) {
    __syncthreads();
    #pragma unroll
    for (int t = 0; t < 4; ++t)
      async_copy16(Ag + (size_t)(t * 32) * lda + kt * 64, &Asm[(t * 32 + wave * 8) * 64]);
    #pragma unroll
    for (int t = 0; t < 4; ++t)
      async_copy16(Wg + (size_t)(t * 32) * lda + kt * 64, &Bsm[(t * 32 + wave * 8) * 64]);
    __syncthreads();

    #pragma unroll
    for (int ks = 0; ks < 2; ++ks) {
      const int kcol = ks * 32 + (lane >> 4) * 8;
      bf16x8 af[4], bfv[4];
      #pragma unroll
      for (int mt = 0; mt < 4; mt++)
        af[mt] = *(const bf16x8*)&Asm[(wm * 64 + mt * 16 + (lane & 15)) * 64 + kcol];
      #pragma unroll
      for (int nt = 0; nt < 4; nt++)
        bfv[nt] = *(const bf16x8*)&Bsm[(wn * 64 + nt * 16 + (lane & 15)) * 64 + kcol];
      #pragma unroll
      for (int mt = 0; mt < 4; mt++)
        #pragma unroll
        for (int nt = 0; nt < 4; nt++)
          acc[mt][nt] = __builtin_amdgcn_mfma_f32_16x16x32_bf16(af[mt], bfv[nt], acc[mt][nt], 0, 0, 0);
    }
  }

  #pragma unroll
  for (int mt = 0; mt < 4; mt++) {
    #pragma unroll
    for (int nt = 0; nt < 4; nt++) {
      const int col = bn * 128 + wn * 64 + nt * 16 + (lane & 15);
      const float bv = bias[col];
      #pragma unroll
      for (int i = 0; i < 4; i++) {
        const long row = bm * 128 + wm * 64 + mt * 16 + (lane >> 4) * 4 + i;
        float v = fmaxf(acc[mt][nt][i] + bv, 0.f);
        out[row * (size_t)1024 + col] = f2b(v);
      }
    }
  }
}

// ---------------- q = x2 @ w3^T + b3 (one wave per row) ----------------

__global__ void qdot(const unsigned short* __restrict__ x2, const float* __restrict__ w3,
                     const float* __restrict__ b3, float* __restrict__ q) {
  const int lane = threadIdx.x & 63;
  const long row = (long)blockIdx.x * 4 + (threadIdx.x >> 6);
  const unsigned short* xr = x2 + row * (size_t)1024 + lane * 8;
  bf16x8 v0 = *(const bf16x8*)xr;
  bf16x8 v1 = *(const bf16x8*)(xr + 512);
  float s = 0.f;
  #pragma unroll
  for (int j = 0; j < 8; j++) {
    s += b2f((unsigned short)v0[j]) * w3[lane * 8 + j];
    s += b2f((unsigned short)v1[j]) * w3[512 + lane * 8 + j];
  }
  #pragma unroll
  for (int off = 32; off > 0; off >>= 1) s += __shfl_down(s, off, 64);
  if (lane == 0) q[row] = s + b3[0];
}

// ---------------- launch ----------------

extern "C" void kernel_launch(void* const* d_in, const int* in_sizes, int n_in,
                              void* d_out, int out_size, void* d_ws, size_t ws_size,
                              hipStream_t stream) {
  const float* state  = (const float*)d_in[0];
  const float* action = (const float*)d_in[1];
  const float* hidden = (const float*)d_in[2];
  const float* w_ih   = (const float*)d_in[3];
  const float* w_hh   = (const float*)d_in[4];
  const float* b_ih   = (const float*)d_in[5];
  const float* b_hh   = (const float*)d_in[6];
  const float* w1     = (const float*)d_in[7];
  const float* b1     = (const float*)d_in[8];
  const float* w2     = (const float*)d_in[9];
  const float* b2     = (const float*)d_in[10];
  const float* w3     = (const float*)d_in[11];
  const float* b3     = (const float*)d_in[12];

  float* q_out = (float*)d_out;
  float* h_out = q_out + BATCH;

  char* ws = (char*)d_ws;
  // region 0 [0, 128MB): Acat (109 MB) in phase 1, then reused as x1 (128 MB)
  unsigned short* Acat = (unsigned short*)(ws + 0);
  unsigned short* x1   = (unsigned short*)(ws + 0);
  // region 1 [128MB, 256MB): x2 (128 MB)
  unsigned short* x2   = (unsigned short*)(ws + 134217728);
  // region 2 [256MB, 320MB): hnb (64 MB)
  unsigned short* hnb  = (unsigned short*)(ws + 268435456);
  // region 3: packed weights
  unsigned short* Wrz  = (unsigned short*)(ws + 335544320);    // 1024x832 bf16
  unsigned short* Wn   = (unsigned short*)(ws + 337248256);    // 512x832 bf16
  unsigned short* w1b  = (unsigned short*)(ws + 338100224);    // 1024x512 bf16
  unsigned short* w2b  = (unsigned short*)(ws + 339148800);    // 1024x1024 bf16

  pack_A<<<26624, 256, 0, stream>>>(state, action, hidden, Acat);
  pack_W<<<624, 256, 0, stream>>>(w_ih, w_hh, Wrz, Wn);
  pack_w12<<<768, 256, 0, stream>>>(w1, w2, w1b, w2b);

  // fused GRU: r,z,i_n,h_n GEMMs (K=832) + GRU cell -> h_out (f32) + hnb (bf16)
  gru_fused<<<4096, 256, 0, stream>>>(Acat, Wrz, Wn, b_ih, b_hh, h_out, hnb);
  // x1 = relu(h_new @ w1^T + b1)  K=512   (writes over Acat region; Acat is dead)
  gemm_bt<8><<<4096, 256, 0, stream>>>(hnb, w1b, b1, x1, 512);
  // x2 = relu(x1 @ w2^T + b2)     K=1024
  gemm_bt<16><<<4096, 256, 0, stream>>>(x1, w2b, b2, x2, 1024);
  // q = x2 @ w3^T + b3
  qdot<<<16384, 256, 0, stream>>>(x2, w3, b3, q_out);
}

// Round 3
// 749.773 us; speedup vs baseline: 1.2897x; 1.0956x over previous
//
#include <hip/hip_runtime.h>
#include <stdint.h>

#define BATCH 65536
#define KCAT 832   // 320 (state+action) + 512 (h)

typedef __attribute__((ext_vector_type(8))) short bf16x8;
typedef __attribute__((ext_vector_type(4))) float f32x4;

typedef __attribute__((address_space(3))) void lds_void_t;
typedef __attribute__((address_space(1))) void glob_void_t;

__device__ __forceinline__ void async_copy16(const void* g, void* l) {
  __builtin_amdgcn_global_load_lds((glob_void_t*)(uintptr_t)g,
                                   (lds_void_t*)(uint32_t)(uintptr_t)l, 16, 0, 0);
}

__device__ __forceinline__ float b2f(unsigned short u) {
  union { uint32_t i; float f; } c; c.i = ((uint32_t)u) << 16; return c.f;
}
__device__ __forceinline__ unsigned short f2b(float f) {
  uint32_t x = __float_as_uint(f);
  uint32_t r = (x + 0x7fffu + ((x >> 16) & 1u)) >> 16;
  return (unsigned short)r;
}

// ---------------- prep kernels ----------------

__global__ void pack_A(const float* __restrict__ state, const float* __restrict__ action,
                       const float* __restrict__ hidden, unsigned short* __restrict__ Acat) {
  long t = (long)blockIdx.x * 256 + threadIdx.x;   // 65536*104 threads
  int seg = (int)(t % 104); long row = t / 104;
  int col = seg * 8;
  const float* src;
  if (col < 256)       src = state  + row * 256 + col;
  else if (col < 320)  src = action + row * 64  + (col - 256);
  else                 src = hidden + row * 512 + (col - 320);
  bf16x8 o;
  #pragma unroll
  for (int j = 0; j < 8; j++) o[j] = (short)f2b(src[j]);
  *(bf16x8*)(Acat + row * (size_t)KCAT + col) = o;
}

__global__ void pack_W(const float* __restrict__ w_ih, const float* __restrict__ w_hh,
                       unsigned short* __restrict__ Wrz, unsigned short* __restrict__ Wn) {
  long t = (long)blockIdx.x * 256 + threadIdx.x;   // 1536*104 threads
  int seg = (int)(t % 104); int j = (int)(t / 104); // row 0..1535
  int col = seg * 8;
  const float* src = (col < 320) ? (w_ih + (long)j * 320 + col)
                                 : (w_hh + (long)j * 512 + (col - 320));
  unsigned short* dst = (j < 1024) ? (Wrz + (long)j * KCAT + col)
                                   : (Wn + (long)(j - 1024) * KCAT + col);
  bf16x8 o;
  #pragma unroll
  for (int jj = 0; jj < 8; jj++) o[jj] = (short)f2b(src[jj]);
  *(bf16x8*)dst = o;
}

// also initializes q_out to b3 (G4 accumulates into it atomically)
__global__ void pack_w12(const float* __restrict__ w1, const float* __restrict__ w2,
                         const float* __restrict__ b3,
                         unsigned short* __restrict__ w1b, unsigned short* __restrict__ w2b,
                         float* __restrict__ q) {
  long t = (long)blockIdx.x * 256 + threadIdx.x;   // 262144 threads
  if (t < 65536) {
    const float* s = w1 + t * 8; unsigned short* d = w1b + t * 8;
    bf16x8 o;
    #pragma unroll
    for (int j = 0; j < 8; j++) o[j] = (short)f2b(s[j]);
    *(bf16x8*)d = o;
  } else if (t < 196608) {
    long t2 = t - 65536;
    const float* s = w2 + t2 * 8; unsigned short* d = w2b + t2 * 8;
    bf16x8 o;
    #pragma unroll
    for (int j = 0; j < 8; j++) o[j] = (short)f2b(s[j]);
    *(bf16x8*)d = o;
  } else {
    q[t - 196608] = b3[0];
  }
}

// ---------------- fused GRU: r,z,n GEMMs + elementwise ----------------
// Per block: 128 rows x 64 gate-cols. Accumulates r,z (K=832) and i_n (K=320),
// h_n (K=512) in registers; epilogue applies the full GRU cell.
// LDS k-segments XOR-swizzled by (row&7) to kill ds_read_b128 bank conflicts.

__global__ __launch_bounds__(256, 2) void gru_fused(
    const unsigned short* __restrict__ A,    // A_cat [BATCH x 832] bf16
    const unsigned short* __restrict__ Wrz,  // [1024 x 832] bf16 (r rows 0..511, z rows 512..1023)
    const unsigned short* __restrict__ Wn,   // [512 x 832] bf16
    const float* __restrict__ b_ih, const float* __restrict__ b_hh,
    float* __restrict__ hnew_f,              // d_out + BATCH, f32 [BATCH x 512]
    unsigned short* __restrict__ hnew_b)     // bf16 copy for next GEMM
{
  __shared__ unsigned short Asm[128 * 64];       // 16 KB
  __shared__ unsigned short Wsm[3 * 64 * 64];    // 24 KB (r | z | n)
  const int tid = threadIdx.x;
  const int wave = tid >> 6, lane = tid & 63;
  const int wm = wave >> 1, wn = wave & 1;

  const int bid = blockIdx.x;
  const int xcd = bid & 7;
  const int j = bid >> 3;          // 0..511 per-XCD work id
  const int bn = j & 7;            // 8 col tiles of 64
  const long bm = (long)xcd * 64 + (j >> 3);   // 512 row tiles of 128

  const int srow = lane >> 3;                       // 0..7
  const int scol = (((lane & 7) ^ srow)) * 8;       // swizzled k-segment fetched by this lane

  f32x4 accR[4][2], accZ[4][2], accI[4][2], accH[4][2];
  #pragma unroll
  for (int i = 0; i < 4; i++)
    #pragma unroll
    for (int t = 0; t < 2; t++) {
      accR[i][t] = (f32x4){0.f,0.f,0.f,0.f}; accZ[i][t] = (f32x4){0.f,0.f,0.f,0.f};
      accI[i][t] = (f32x4){0.f,0.f,0.f,0.f}; accH[i][t] = (f32x4){0.f,0.f,0.f,0.f};
    }

  const unsigned short* Ag  = A   + (bm * 128 + wave * 8 + srow) * (size_t)KCAT + scol;
  const unsigned short* Wrg = Wrz + ((size_t)bn * 64 + wave * 8 + srow) * KCAT + scol;
  const unsigned short* Wzg = Wrz + ((size_t)512 + bn * 64 + wave * 8 + srow) * KCAT + scol;
  const unsigned short* Wng = Wn  + ((size_t)bn * 64 + wave * 8 + srow) * KCAT + scol;

  const int rlo = lane & 15;
  const int quad = lane >> 4;

  for (int kt = 0; kt < 13; ++kt) {
    __syncthreads();
    #pragma unroll
    for (int t = 0; t < 4; ++t)
      async_copy16(Ag + (size_t)(t * 32) * KCAT + kt * 64, &Asm[(t * 32 + wave * 8) * 64]);
    #pragma unroll
    for (int t = 0; t < 2; ++t) {
      async_copy16(Wrg + (size_t)(t * 32) * KCAT + kt * 64, &Wsm[0 * 4096 + (t * 32 + wave * 8) * 64]);
      async_copy16(Wzg + (size_t)(t * 32) * KCAT + kt * 64, &Wsm[1 * 4096 + (t * 32 + wave * 8) * 64]);
      async_copy16(Wng + (size_t)(t * 32) * KCAT + kt * 64, &Wsm[2 * 4096 + (t * 32 + wave * 8) * 64]);
    }
    __syncthreads();

    #pragma unroll
    for (int ks = 0; ks < 2; ++ks) {
      const int kseg = ks * 4 + quad;                 // global k-segment 0..7
      const int sw = (kseg ^ (rlo & 7)) * 8;          // swizzled LDS element offset
      bf16x8 af[4], bR[2], bZ[2], bN[2];
      #pragma unroll
      for (int mt = 0; mt < 4; mt++)
        af[mt] = *(const bf16x8*)&Asm[(wm * 64 + mt * 16 + rlo) * 64 + sw];
      #pragma unroll
      for (int nt = 0; nt < 2; nt++) {
        const int wrow = (wn * 32 + nt * 16 + rlo) * 64 + sw;
        bR[nt] = *(const bf16x8*)&Wsm[0 * 4096 + wrow];
        bZ[nt] = *(const bf16x8*)&Wsm[1 * 4096 + wrow];
        bN[nt] = *(const bf16x8*)&Wsm[2 * 4096 + wrow];
      }
      #pragma unroll
      for (int mt = 0; mt < 4; mt++)
        #pragma unroll
        for (int nt = 0; nt < 2; nt++) {
          accR[mt][nt] = __builtin_amdgcn_mfma_f32_16x16x32_bf16(af[mt], bR[nt], accR[mt][nt], 0, 0, 0);
          accZ[mt][nt] = __builtin_amdgcn_mfma_f32_16x16x32_bf16(af[mt], bZ[nt], accZ[mt][nt], 0, 0, 0);
        }
      if (kt < 5) {   // k in [0,320): state+action part -> i_n
        #pragma unroll
        for (int mt = 0; mt < 4; mt++)
          #pragma unroll
          for (int nt = 0; nt < 2; nt++)
            accI[mt][nt] = __builtin_amdgcn_mfma_f32_16x16x32_bf16(af[mt], bN[nt], accI[mt][nt], 0, 0, 0);
      } else {        // k in [320,832): h part -> h_n
        #pragma unroll
        for (int mt = 0; mt < 4; mt++)
          #pragma unroll
          for (int nt = 0; nt < 2; nt++)
            accH[mt][nt] = __builtin_amdgcn_mfma_f32_16x16x32_bf16(af[mt], bN[nt], accH[mt][nt], 0, 0, 0);
      }
    }
  }

  // epilogue: C/D layout col=lane&15, row=quad*4+reg
  const long rowbase = bm * 128 + wm * 64;
  const int colbase = bn * 64 + wn * 32;
  #pragma unroll
  for (int mt = 0; mt < 4; mt++) {
    #pragma unroll
    for (int nt = 0; nt < 2; nt++) {
      const int col = colbase + nt * 16 + rlo;   // 0..511
      const float brv = b_ih[col] + b_hh[col];
      const float bzv = b_ih[512 + col] + b_hh[512 + col];
      const float bin = b_ih[1024 + col];
      const float bhn = b_hh[1024 + col];
      #pragma unroll
      for (int i = 0; i < 4; i++) {
        const long row = rowbase + mt * 16 + quad * 4 + i;
        const float r = 1.f / (1.f + __expf(-(accR[mt][nt][i] + brv)));
        const float z = 1.f / (1.f + __expf(-(accZ[mt][nt][i] + bzv)));
        const float x = (accI[mt][nt][i] + bin) + r * (accH[mt][nt][i] + bhn);
        const float n = 1.f - 2.f / (__expf(2.f * x) + 1.f);   // tanh(x)
        const float h = b2f(A[row * (size_t)KCAT + 320 + col]); // h in bf16 from A_cat
        const float hv = (1.f - z) * n + z * h;
        hnew_f[row * (size_t)512 + col] = hv;
        hnew_b[row * (size_t)512 + col] = f2b(hv);
      }
    }
  }
}

// ---------------- generic TN GEMM: relu(A @ W^T + bias) ----------------
// 128x128 tile, BK=64, XCD-swizzled 1-D grid of 4096 (M=65536, N=1024).
// QFUSE=0: store bf16. QFUSE=1: don't store; q[row] += relu(v) . w3[col] (atomic).

template<int KT, int QFUSE>
__global__ __launch_bounds__(256, 2) void gemm_bt(
    const unsigned short* __restrict__ A, const unsigned short* __restrict__ W,
    const float* __restrict__ bias, unsigned short* __restrict__ out,
    int lda, const float* __restrict__ w3, float* __restrict__ q)
{
  __shared__ unsigned short Asm[128 * 64];
  __shared__ unsigned short Bsm[128 * 64];
  const int tid = threadIdx.x;
  const int wave = tid >> 6, lane = tid & 63;
  const int wm = wave >> 1, wn = wave & 1;

  const int bid = blockIdx.x;
  const int xcd = bid & 7;
  const int j = bid >> 3;
  const int bn = j & 7;                        // 8 col tiles of 128 (N=1024)
  const long bm = (long)xcd * 64 + (j >> 3);   // 512 row tiles of 128

  const int srow = lane >> 3;
  const int scol = (((lane & 7) ^ srow)) * 8;  // swizzled fetch segment

  f32x4 acc[4][4];
  #pragma unroll
  for (int i = 0; i < 4; i++)
    #pragma unroll
    for (int t = 0; t < 4; t++) acc[i][t] = (f32x4){0.f, 0.f, 0.f, 0.f};

  const unsigned short* Ag = A + (bm * 128 + wave * 8 + srow) * (size_t)lda + scol;
  const unsigned short* Wg = W + ((size_t)bn * 128 + wave * 8 + srow) * lda + scol;

  const int rlo = lane & 15;
  const int quad = lane >> 4;

  for (int kt = 0; kt < KT; ++kt) {
    __syncthreads();
    #pragma unroll
    for (int t = 0; t < 4; ++t)
      async_copy16(Ag + (size_t)(t * 32) * lda + kt * 64, &Asm[(t * 32 + wave * 8) * 64]);
    #pragma unroll
    for (int t = 0; t < 4; ++t)
      async_copy16(Wg + (size_t)(t * 32) * lda + kt * 64, &Bsm[(t * 32 + wave * 8) * 64]);
    __syncthreads();

    #pragma unroll
    for (int ks = 0; ks < 2; ++ks) {
      const int kseg = ks * 4 + quad;
      const int sw = (kseg ^ (rlo & 7)) * 8;
      bf16x8 af[4], bfv[4];
      #pragma unroll
      for (int mt = 0; mt < 4; mt++)
        af[mt] = *(const bf16x8*)&Asm[(wm * 64 + mt * 16 + rlo) * 64 + sw];
      #pragma unroll
      for (int nt = 0; nt < 4; nt++)
        bfv[nt] = *(const bf16x8*)&Bsm[(wn * 64 + nt * 16 + rlo) * 64 + sw];
      #pragma unroll
      for (int mt = 0; mt < 4; mt++)
        #pragma unroll
        for (int nt = 0; nt < 4; nt++)
          acc[mt][nt] = __builtin_amdgcn_mfma_f32_16x16x32_bf16(af[mt], bfv[nt], acc[mt][nt], 0, 0, 0);
    }
  }

  if (QFUSE == 0) {
    #pragma unroll
    for (int mt = 0; mt < 4; mt++) {
      #pragma unroll
      for (int nt = 0; nt < 4; nt++) {
        const int col = bn * 128 + wn * 64 + nt * 16 + rlo;
        const float bv = bias[col];
        #pragma unroll
        for (int i = 0; i < 4; i++) {
          const long row = bm * 128 + wm * 64 + mt * 16 + quad * 4 + i;
          float v = fmaxf(acc[mt][nt][i] + bv, 0.f);
          out[row * (size_t)1024 + col] = f2b(v);
        }
      }
    }
  } else {
    // fused final dot: q[row] += sum_col relu(v) * w3[col]
    float bv[4], w3v[4];
    #pragma unroll
    for (int nt = 0; nt < 4; nt++) {
      const int col = bn * 128 + wn * 64 + nt * 16 + rlo;
      bv[nt] = bias[col];
      w3v[nt] = w3[col];
    }
    #pragma unroll
    for (int mt = 0; mt < 4; mt++) {
      #pragma unroll
      for (int i = 0; i < 4; i++) {
        float s = 0.f;
        #pragma unroll
        for (int nt = 0; nt < 4; nt++)
          s += fmaxf(acc[mt][nt][i] + bv[nt], 0.f) * w3v[nt];
        // reduce the 16 lanes of the quad (same row, different cols)
        #pragma unroll
        for (int off = 1; off < 16; off <<= 1) s += __shfl_xor(s, off, 64);
        if (rlo == 0) {
          const long row = bm * 128 + wm * 64 + mt * 16 + quad * 4 + i;
          atomicAdd(&q[row], s);
        }
      }
    }
  }
}

// ---------------- launch ----------------

extern "C" void kernel_launch(void* const* d_in, const int* in_sizes, int n_in,
                              void* d_out, int out_size, void* d_ws, size_t ws_size,
                              hipStream_t stream) {
  const float* state  = (const float*)d_in[0];
  const float* action = (const float*)d_in[1];
  const float* hidden = (const float*)d_in[2];
  const float* w_ih   = (const float*)d_in[3];
  const float* w_hh   = (const float*)d_in[4];
  const float* b_ih   = (const float*)d_in[5];
  const float* b_hh   = (const float*)d_in[6];
  const float* w1     = (const float*)d_in[7];
  const float* b1     = (const float*)d_in[8];
  const float* w2     = (const float*)d_in[9];
  const float* b2     = (const float*)d_in[10];
  const float* w3     = (const float*)d_in[11];
  const float* b3     = (const float*)d_in[12];

  float* q_out = (float*)d_out;
  float* h_out = q_out + BATCH;

  char* ws = (char*)d_ws;
  // region 0 [0, 128MB): Acat (109 MB) in phase 1, then reused as x1 (128 MB)
  unsigned short* Acat = (unsigned short*)(ws + 0);
  unsigned short* x1   = (unsigned short*)(ws + 0);
  // region 2 [256MB, 320MB): hnb (64 MB)
  unsigned short* hnb  = (unsigned short*)(ws + 268435456);
  // region 3: packed weights
  unsigned short* Wrz  = (unsigned short*)(ws + 335544320);    // 1024x832 bf16
  unsigned short* Wn   = (unsigned short*)(ws + 337248256);    // 512x832 bf16
  unsigned short* w1b  = (unsigned short*)(ws + 338100224);    // 1024x512 bf16
  unsigned short* w2b  = (unsigned short*)(ws + 339148800);    // 1024x1024 bf16

  pack_A<<<26624, 256, 0, stream>>>(state, action, hidden, Acat);
  pack_W<<<624, 256, 0, stream>>>(w_ih, w_hh, Wrz, Wn);
  pack_w12<<<1024, 256, 0, stream>>>(w1, w2, b3, w1b, w2b, q_out);

  // fused GRU: r,z,i_n,h_n GEMMs (K=832) + GRU cell -> h_out (f32) + hnb (bf16)
  gru_fused<<<4096, 256, 0, stream>>>(Acat, Wrz, Wn, b_ih, b_hh, h_out, hnb);
  // x1 = relu(h_new @ w1^T + b1)  K=512   (writes over Acat region; Acat is dead)
  gemm_bt<8, 0><<<4096, 256, 0, stream>>>(hnb, w1b, b1, x1, 512, nullptr, nullptr);
  // q += relu(x1 @ w2^T + b2) . w3  K=1024  (x2 never materialized)
  gemm_bt<16, 1><<<4096, 256, 0, stream>>>(x1, w2b, b2, nullptr, 1024, w3, q_out);
}